// Round 5
// baseline (226.236 us; speedup 1.0000x reference)
//
#include <hip/hip_runtime.h>
#include <stdint.h>

typedef unsigned int uint;
typedef unsigned short ushort_t;
typedef float f32x4 __attribute__((ext_vector_type(4)));

#define NPTS 500000
#define NC 256
#define SPAIRS 600000
#define FS 14
#define F3 2744            // 14^3
#define VOXT (NC * F3)     // 702464
#define QV8 343            // F3/8 voxels per k_out block
#define CHUNK 288          // pairs staged per LDS chunk in k_out

// ---------- helpers ----------
__device__ __forceinline__ uint encF(float f) {
    uint u = __float_as_uint(f);
    return (u & 0x80000000u) ? ~u : (u | 0x80000000u);
}
__device__ __forceinline__ float decF(uint e) {
    uint u = (e & 0x80000000u) ? (e ^ 0x80000000u) : ~e;
    return __uint_as_float(u);
}
// ids may arrive as int32 (jax x64 off) or int64. Sorted cids: mid values ~128,
// so for int64 the odd int32 words (high) are 0; for int32 they're nonzero.
__device__ __forceinline__ uint detect64(const void* cids) {
    const int* p = (const int*)cids;
    int z = 0;
    #pragma unroll
    for (int k = 0; k < 5; ++k) z += (p[300001 + 2 * k] == 0) ? 1 : 0;
    return (z >= 3) ? 1u : 0u;
}
__device__ __forceinline__ int loadId(const void* p, int i, uint is64) {
    return is64 ? (int)((const long long*)p)[i] : ((const int*)p)[i];
}

// ---------- kernel 1: per-cluster count/sum(f64)/min/max — wave-segmented reduce ----------
__global__ __launch_bounds__(256) void k_stats(const void* cids, const void* pids,
        const float* coords,
        double* gsum, uint* gcnt, uint* gmin, uint* gmax) {
    __shared__ double sSum[NC][3];
    __shared__ uint   sCnt[NC];
    __shared__ uint   sMin[NC][3];
    __shared__ uint   sMax[NC][3];
    int tid = threadIdx.x;
    for (int c = tid; c < NC; c += 256) {
        sCnt[c] = 0u;
        for (int d = 0; d < 3; ++d) { sSum[c][d] = 0.0; sMin[c][d] = 0xFFFFFFFFu; sMax[c][d] = 0u; }
    }
    __syncthreads();
    uint is64 = detect64(cids);
    int s = blockIdx.x * 256 + tid;
    bool valid = s < SPAIRS;
    int sc = valid ? s : SPAIRS - 1;
    int cid = loadId(cids, sc, is64);
    int pid = loadId(pids, sc, is64);
    float x = coords[3 * pid + 0];
    float y = coords[3 * pid + 1];
    float z = coords[3 * pid + 2];
    int lane = tid & 63;
    int cid0 = __shfl(cid, 0, 64), cid63 = __shfl(cid, 63, 64);
    if (cid0 == cid63) {
        uint nval = (uint)__popcll(__ballot(valid));
        double dx = valid ? (double)x : 0.0;
        double dy = valid ? (double)y : 0.0;
        double dz = valid ? (double)z : 0.0;
        float mnx = valid ? x : INFINITY,  mny = valid ? y : INFINITY,  mnz = valid ? z : INFINITY;
        float mxx = valid ? x : -INFINITY, mxy = valid ? y : -INFINITY, mxz = valid ? z : -INFINITY;
        #pragma unroll
        for (int st = 1; st < 64; st <<= 1) {
            dx += __shfl_xor(dx, st, 64);
            dy += __shfl_xor(dy, st, 64);
            dz += __shfl_xor(dz, st, 64);
            mnx = fminf(mnx, __shfl_xor(mnx, st, 64));
            mny = fminf(mny, __shfl_xor(mny, st, 64));
            mnz = fminf(mnz, __shfl_xor(mnz, st, 64));
            mxx = fmaxf(mxx, __shfl_xor(mxx, st, 64));
            mxy = fmaxf(mxy, __shfl_xor(mxy, st, 64));
            mxz = fmaxf(mxz, __shfl_xor(mxz, st, 64));
        }
        if (lane == 0 && nval) {
            atomicAdd(&sCnt[cid0], nval);
            unsafeAtomicAdd(&sSum[cid0][0], dx);
            unsafeAtomicAdd(&sSum[cid0][1], dy);
            unsafeAtomicAdd(&sSum[cid0][2], dz);
            atomicMin(&sMin[cid0][0], encF(mnx)); atomicMin(&sMin[cid0][1], encF(mny)); atomicMin(&sMin[cid0][2], encF(mnz));
            atomicMax(&sMax[cid0][0], encF(mxx)); atomicMax(&sMax[cid0][1], encF(mxy)); atomicMax(&sMax[cid0][2], encF(mxz));
        }
    } else if (valid) {
        atomicAdd(&sCnt[cid], 1u);
        unsafeAtomicAdd(&sSum[cid][0], (double)x);
        unsafeAtomicAdd(&sSum[cid][1], (double)y);
        unsafeAtomicAdd(&sSum[cid][2], (double)z);
        atomicMin(&sMin[cid][0], encF(x)); atomicMin(&sMin[cid][1], encF(y)); atomicMin(&sMin[cid][2], encF(z));
        atomicMax(&sMax[cid][0], encF(x)); atomicMax(&sMax[cid][1], encF(y)); atomicMax(&sMax[cid][2], encF(z));
    }
    __syncthreads();
    for (int c = tid; c < NC; c += 256) {
        if (sCnt[c]) {
            atomicAdd(&gcnt[c], sCnt[c]);
            for (int d = 0; d < 3; ++d) {
                unsafeAtomicAdd(&gsum[c * 3 + d], sSum[c][d]);
                atomicMin(&gmin[c * 3 + d], sMin[c][d]);
                atomicMax(&gmax[c * 3 + d], sMax[c][d]);
            }
        }
    }
}

// ---------- kernel 2: per-cluster mean/scale/offset (double) + parallel prefix for coff ----------
__global__ void k_params(const double* gsum, const uint* gcnt, const uint* gmin,
                         const uint* gmax, double* params, int* coff) {
    __shared__ uint wsum[4];
    int c = threadIdx.x;                 // exactly 256 threads
    uint n = gcnt[c];
    double mean[3] = {0, 0, 0}, off[3] = {0, 0, 0}, scale = 50.0;
    if (n) {
        double dn = (double)n;
        double r = 0.0, mn[3];
        for (int d = 0; d < 3; ++d) {
            mean[d] = gsum[c * 3 + d] / dn;
            mn[d] = (double)decF(gmin[c * 3 + d]) - mean[d];
            double mx = (double)decF(gmax[c * 3 + d]) - mean[d];
            double ext = (mx - mn[d]) / (double)FS;
            r = fmax(r, ext);
        }
        double sr = 1.0 / r - 0.01;      // r==0 -> inf -> clamp to 50
        scale = fmin(sr, 50.0);
        for (int d = 0; d < 3; ++d) off[d] = -(mn[d] * scale);
    }
    params[c * 8 + 0] = mean[0]; params[c * 8 + 1] = mean[1]; params[c * 8 + 2] = mean[2];
    params[c * 8 + 3] = scale;
    params[c * 8 + 4] = off[0];  params[c * 8 + 5] = off[1];  params[c * 8 + 6] = off[2];
    params[c * 8 + 7] = 0.0;

    uint incl = n;
    #pragma unroll
    for (int d = 1; d < 64; d <<= 1) {
        uint y = __shfl_up(incl, d, 64);
        if ((c & 63) >= d) incl += y;
    }
    int w = c >> 6;
    if ((c & 63) == 63) wsum[w] = incl;
    __syncthreads();
    uint woff = 0;
    #pragma unroll
    for (int i = 0; i < 4; ++i) if (i < w) woff += wsum[i];
    coff[c] = (int)(incl - n + woff);
    if (c == 255) coff[NC] = (int)(incl + woff);
}

// ---------- kernel 3: per-pair local voxel id + rank + per-voxel count ----------
__global__ __launch_bounds__(256) void k_vox(const void* cids, const void* pids,
        const float* coords, const double* params,
        ushort_t* vidl, ushort_t* rankl, uint* vptr) {
    int s = blockIdx.x * blockDim.x + threadIdx.x;
    if (s >= SPAIRS) return;
    uint is64 = detect64(cids);
    int cid = loadId(cids, s, is64);
    int pid = loadId(pids, s, is64);
    const double* P = params + cid * 8;
    float cx = coords[3 * pid + 0];
    float cy = coords[3 * pid + 1];
    float cz = coords[3 * pid + 2];
    double vx = ((double)cx - P[0]) * P[3] + P[4];
    double vy = ((double)cy - P[1]) * P[3] + P[5];
    double vz = ((double)cz - P[2]) * P[3] + P[6];
    int ix = (int)floor(vx); ix = ix < 0 ? 0 : (ix > FS - 1 ? FS - 1 : ix);
    int iy = (int)floor(vy); iy = iy < 0 ? 0 : (iy > FS - 1 ? FS - 1 : iy);
    int iz = (int)floor(vz); iz = iz < 0 ? 0 : (iz > FS - 1 ? FS - 1 : iz);
    int v = (ix * FS + iy) * FS + iz;
    vidl[s] = (ushort_t)v;
    uint r = atomicAdd(&vptr[cid * F3 + v], 1u);   // rank within voxel (max < cluster size < 64K)
    rankl[s] = (ushort_t)r;
}

// ---------- kernel 4: per-cluster exclusive scan of vptr (+coff base) + sentinel + agg zero ----------
__global__ __launch_bounds__(256) void k_scan(const int* coff, uint* vptr, uint* agg) {
    __shared__ uint wsum[4];
    int c = blockIdx.x, t = threadIdx.x;
    uint* base = vptr + c * F3;
    int b0 = t * 11;                 // 11*256 = 2816 >= F3
    uint v[11];
    uint s = 0;
    #pragma unroll
    for (int i = 0; i < 11; ++i) {
        int idx = b0 + i;
        uint x = (idx < F3) ? base[idx] : 0u;
        v[i] = s;
        s += x;
    }
    uint run = s;
    #pragma unroll
    for (int d = 1; d < 64; d <<= 1) {
        uint y = __shfl_up(run, d, 64);
        if ((t & 63) >= d) run += y;
    }
    int w = t >> 6;
    if ((t & 63) == 63) wsum[w] = run;
    __syncthreads();
    uint woff = 0;
    #pragma unroll
    for (int i = 0; i < 4; ++i) if (i < w) woff += wsum[i];
    uint excl = run - s + woff + (uint)coff[c];
    #pragma unroll
    for (int i = 0; i < 11; ++i) {
        int idx = b0 + i;
        if (idx < F3) base[idx] = excl + v[i];   // exclusive start per voxel
    }
    if (c == 255 && t == 0) vptr[VOXT] = (uint)coff[NC];   // sentinel
    if (t < 32) agg[c * 32 + t] = 0u;                      // agg-enc zero (replaces memset)
}

// ---------- kernel 5: scatter (atomic-free, deterministic): spid sorted by (cluster,voxel) ----------
__global__ __launch_bounds__(256) void k_scatter(const void* cids, const void* pids,
        const ushort_t* vidl, const ushort_t* rankl, const uint* vptr, int* spid) {
    int s = blockIdx.x * blockDim.x + threadIdx.x;
    if (s >= SPAIRS) return;
    uint is64 = detect64(cids);
    int cid = loadId(cids, s, is64);
    int pid = loadId(pids, s, is64);
    int vid = cid * F3 + (int)vidl[s];
    uint pos = vptr[vid] + (uint)rankl[s];
    spid[pos] = pid;
}

// ---------- kernel 6: LDS-staged per-voxel sum + mean + agg-max ----------
// Block = cluster-eighth (343 voxels, ~293 pairs). Phases: stage feats rows into
// LDS (8 lanes x 16B per pair, XOR-swizzled rows -> bank-optimal), then per-voxel
// register accumulate from LDS, then streaming NT writes. Grid 2048, XCD-swizzled.
__global__ __launch_bounds__(256) void k_out(const float4* feats4, const uint* vptr,
        const int* spid, float* out, uint* agg) {
    __shared__ uint   sVptr[344];
    __shared__ float4 sF[CHUNK * 8];   // 36864 B
    __shared__ float  red[4][32];
    int b = blockIdx.x;
    int xcd = b & 7, r = b >> 3;
    int c = xcd * 32 + (r >> 3);     // cluster
    int p = r & 7;                   // eighth
    int t = threadIdx.x;
    int vid0 = c * F3 + p * QV8;

    sVptr[t] = vptr[vid0 + t];
    if (t < 88) sVptr[256 + t] = vptr[vid0 + 256 + t];
    __syncthreads();
    uint S0 = sVptr[0], S1 = sVptr[343];

    // owned voxels: lv0 = t; lv1 = 256+t (t<87)
    uint vs0 = sVptr[t],  ve0 = sVptr[t + 1];
    bool has1 = t < 87;
    uint vs1 = has1 ? sVptr[256 + t] : 0u;
    uint ve1 = has1 ? sVptr[257 + t] : 0u;

    float4 acc0[8], acc1[8], mx[8];
    #pragma unroll
    for (int g = 0; g < 8; ++g) {
        acc0[g] = make_float4(0.f, 0.f, 0.f, 0.f);
        acc1[g] = make_float4(0.f, 0.f, 0.f, 0.f);
        mx[g]   = make_float4(-INFINITY, -INFINITY, -INFINITY, -INFINITY);
    }

    for (uint cb = S0; cb < S1; cb += CHUNK) {
        int cn = (int)min((uint)CHUNK, S1 - cb);
        // stage: 8 lanes per pair load its contiguous 128B feats row; swizzled LDS row
        for (int l = t; l < cn * 8; l += 256) {
            int q = l >> 3, g = l & 7;
            int pid = spid[cb + q];
            sF[q * 8 + (g ^ (q & 7))] = feats4[(size_t)pid * 8 + g];
        }
        __syncthreads();
        uint ce = cb + (uint)cn;
        // accumulate owned voxel 0
        for (uint q = max(vs0, cb); q < min(ve0, ce); ++q) {
            int row = (int)(q - cb), sw = row & 7;
            #pragma unroll
            for (int j = 0; j < 8; ++j) {
                float4 f = sF[row * 8 + (j ^ sw)];
                acc0[j].x += f.x; acc0[j].y += f.y; acc0[j].z += f.z; acc0[j].w += f.w;
                mx[j].x = fmaxf(mx[j].x, f.x); mx[j].y = fmaxf(mx[j].y, f.y);
                mx[j].z = fmaxf(mx[j].z, f.z); mx[j].w = fmaxf(mx[j].w, f.w);
            }
        }
        // accumulate owned voxel 1
        if (has1) {
            for (uint q = max(vs1, cb); q < min(ve1, ce); ++q) {
                int row = (int)(q - cb), sw = row & 7;
                #pragma unroll
                for (int j = 0; j < 8; ++j) {
                    float4 f = sF[row * 8 + (j ^ sw)];
                    acc1[j].x += f.x; acc1[j].y += f.y; acc1[j].z += f.z; acc1[j].w += f.w;
                    mx[j].x = fmaxf(mx[j].x, f.x); mx[j].y = fmaxf(mx[j].y, f.y);
                    mx[j].z = fmaxf(mx[j].z, f.z); mx[j].w = fmaxf(mx[j].w, f.w);
                }
            }
        }
        __syncthreads();
    }

    // writeout (nontemporal: write-once stream, keep caches for feats)
    {
        uint n0 = ve0 - vs0;
        float inv = 1.0f / (float)(n0 ? n0 : 1u);
        f32x4* o = (f32x4*)(out + (size_t)(vid0 + t) * 32);
        #pragma unroll
        for (int g = 0; g < 8; ++g) {
            f32x4 x = {acc0[g].x * inv, acc0[g].y * inv, acc0[g].z * inv, acc0[g].w * inv};
            __builtin_nontemporal_store(x, o + g);
        }
    }
    if (has1) {
        uint n1 = ve1 - vs1;
        float inv = 1.0f / (float)(n1 ? n1 : 1u);
        f32x4* o = (f32x4*)(out + (size_t)(vid0 + 256 + t) * 32);
        #pragma unroll
        for (int g = 0; g < 8; ++g) {
            f32x4 x = {acc1[g].x * inv, acc1[g].y * inv, acc1[g].z * inv, acc1[g].w * inv};
            __builtin_nontemporal_store(x, o + g);
        }
    }

    // block-wide agg max over 32 channels
    #pragma unroll
    for (int g = 0; g < 8; ++g) {
        #pragma unroll
        for (int st = 1; st < 64; st <<= 1) {
            mx[g].x = fmaxf(mx[g].x, __shfl_xor(mx[g].x, st, 64));
            mx[g].y = fmaxf(mx[g].y, __shfl_xor(mx[g].y, st, 64));
            mx[g].z = fmaxf(mx[g].z, __shfl_xor(mx[g].z, st, 64));
            mx[g].w = fmaxf(mx[g].w, __shfl_xor(mx[g].w, st, 64));
        }
    }
    int wave = t >> 6, lane = t & 63;
    if (lane == 0) {
        #pragma unroll
        for (int g = 0; g < 8; ++g) {
            red[wave][g * 4 + 0] = mx[g].x; red[wave][g * 4 + 1] = mx[g].y;
            red[wave][g * 4 + 2] = mx[g].z; red[wave][g * 4 + 3] = mx[g].w;
        }
    }
    __syncthreads();
    if (t < 32) {
        float m = fmaxf(fmaxf(red[0][t], red[1][t]), fmaxf(red[2][t], red[3][t]));
        if (m != -INFINITY) atomicMax(&agg[c * 32 + t], encF(m));
    }
}

// ---------- kernel 7: agg finalize (decode; untouched/neginf -> 0) ----------
__global__ void k_aggfin(float* outbase) {
    int i = blockIdx.x * blockDim.x + threadIdx.x;     // < NC*32 exactly
    uint* a = (uint*)(outbase + (size_t)VOXT * 32);
    uint e = a[i];
    float f = decF(e);
    if (e == 0u || f == -INFINITY) f = 0.0f;
    ((float*)a)[i] = f;
}

extern "C" void kernel_launch(void* const* d_in, const int* in_sizes, int n_in,
                              void* d_out, int out_size, void* d_ws, size_t ws_size,
                              hipStream_t stream) {
    const float* feats  = (const float*)d_in[0];
    const float* coords = (const float*)d_in[1];
    const void*  cids   = d_in[2];
    const void*  pids   = d_in[3];
    float* out = (float*)d_out;
    char* ws = (char*)d_ws;

    // ws layout (bytes):
    //   0        double gsum[256*3]       (6144)    } zero
    //   6144     uint   gcnt[256]         (1024)    } zero
    //   7168     uint   gmax[256*3]       (3072)    } zero
    //   10240    uint   vptr[VOXT+1]      (2809860) } zero  -> pad 2820160
    //   2820160  uint   gmin[256*3]       (3072)    0xFF
    //   2823232  double params[256*8]     (16384)
    //   2839616  int    coff[257]         (1028 -> pad 2840704)
    //   2840704  u16    vidl[SPAIRS]      (1200000) -> 4040704
    //   4040704  u16    rankl[SPAIRS]     (1200000) -> 5240704
    //   5240704  int    spid[SPAIRS]      (2400000) -> 7640704
    double*   gsum   = (double*)(ws + 0);
    uint*     gcnt   = (uint*)(ws + 6144);
    uint*     gmax   = (uint*)(ws + 7168);
    uint*     vptr   = (uint*)(ws + 10240);
    uint*     gmin   = (uint*)(ws + 2820160);
    double*   params = (double*)(ws + 2823232);
    int*      coff   = (int*)(ws + 2839616);
    ushort_t* vidl   = (ushort_t*)(ws + 2840704);
    ushort_t* rankl  = (ushort_t*)(ws + 4040704);
    int*      spid   = (int*)(ws + 5240704);
    uint*     agg    = (uint*)(out + (size_t)VOXT * 32);

    hipMemsetAsync(ws, 0, 2820160, stream);               // gsum..vptr(+sentinel)
    hipMemsetAsync((void*)gmin, 0xFF, 3072, stream);      // gmin = +max encodings

    int nb = (SPAIRS + 255) / 256;   // 2344
    k_stats<<<nb, 256, 0, stream>>>(cids, pids, coords, gsum, gcnt, gmin, gmax);
    k_params<<<1, 256, 0, stream>>>(gsum, gcnt, gmin, gmax, params, coff);
    k_vox<<<nb, 256, 0, stream>>>(cids, pids, coords, params, vidl, rankl, vptr);
    k_scan<<<NC, 256, 0, stream>>>(coff, vptr, agg);
    k_scatter<<<nb, 256, 0, stream>>>(cids, pids, vidl, rankl, vptr, spid);
    k_out<<<NC * 8, 256, 0, stream>>>((const float4*)feats, vptr, spid, out, agg);
    k_aggfin<<<(NC * 32) / 256, 256, 0, stream>>>(out);
}